// Round 1
// 201.715 us; speedup vs baseline: 1.0185x; 1.0185x over previous
//
#include <hip/hip_runtime.h>

typedef unsigned short u16;
using short8  = __attribute__((ext_vector_type(8))) short;
using floatx4 = __attribute__((ext_vector_type(4))) float;

#define KPAD 104   // LDS row stride (bf16 elems): stride%32=20 -> 2-way (free) frag reads
#define VSTR 96    // global P row stride (bf16 elems): 192 B, 16B-aligned rows

__device__ __forceinline__ u16 f2bf(float f) {
  union { float f; unsigned u; } v; v.f = f;
  unsigned r = v.u + 0x7fffu + ((v.u >> 16) & 1u);   // RNE
  return (u16)(r >> 16);
}

// ---------------- Kernel 0: W_eff = W2@W1, padded to 96x104 bf16 (zeros outside 81x81) ----
__global__ __launch_bounds__(256) void k_weff(const float* __restrict__ W1,
                                              const float* __restrict__ W2,
                                              u16* __restrict__ wepad) {
  int idx = blockIdx.x * 256 + threadIdx.x;
  if (idx >= 96 * 104) return;
  int kp = idx / 104, k = idx - kp * 104;
  float s = 0.f;
  if (kp < 81 && k < 81) {
    #pragma unroll 6
    for (int m = 0; m < 162; ++m)
      s = fmaf(W2[kp * 162 + m], W1[m * 81 + k], s);
  }
  wepad[idx] = (kp < 81 && k < 81) ? f2bf(s) : (u16)0;
}

// ---------------- Kernel 1: fused conv1x1+bias+unfold+res_trans -> P ----------------
// grid (256, 2): block owns 4 complete patches (l = g*4..g*4+3) x 32 out-channels for
// one tensor. Conv in f32 VALU into LDS rows (row = o*4+lp, 81 cols), then one MFMA
// res_trans pass (M=128, N=96, K=96) with LeakyReLU, then fully-coalesced short8
// stores of P (each 128B line of P written by exactly one block -> no cross-XCD
// partial-line interleave, unlike the old scatter-store k_conv).
__global__ __launch_bounds__(256, 2) void k_fused(const float* __restrict__ xg,
                                                  const float* __restrict__ yg,
                                                  const float* __restrict__ Wi,
                                                  const float* __restrict__ bi,
                                                  const float* __restrict__ Wf,
                                                  const float* __restrict__ bfe,
                                                  const u16* __restrict__ wepad,
                                                  u16* __restrict__ Pg) {
  __shared__ float Ws[1024];        //  4096 B
  __shared__ float bs[32];          //   128 B
  __shared__ u16 WeT[96 * KPAD];    // 19968 B
  __shared__ u16 Vs[128 * KPAD];    // 26624 B  (total 50816 B)
  int t = threadIdx.x;
  int tensor = blockIdx.y;
  int g = blockIdx.x;               // patch group, l0 = g*4 (4 | 256 so one pd band)
  const float* src = tensor ? yg : xg;
  const float* Wg  = tensor ? Wf : Wi;
  const float* bg  = tensor ? bfe : bi;

  for (int i = t; i < 1024; i += 256) Ws[i] = Wg[i];
  if (t < 32) bs[t] = bg[t];
  for (int i = t; i < 1248; i += 256)           // 96*104 elems as short8
    *(short8*)&WeT[i * 8] = ((const short8*)wepad)[i];
  if (t < 128) {                                // zero A-operand pad cols 81..95
    #pragma unroll
    for (int cc = 81; cc < 96; ++cc) Vs[t * KPAD + cc] = 0;
  }
  __syncthreads();

  // --- conv1x1 + unfold: 4 patches * 81 voxels = 324 voxels ---
  int l0 = g * 4;
  int pd = l0 >> 8, pw0 = l0 & 255;
  #pragma unroll
  for (int it = 0; it < 2; ++it) {
    int vox = t + it * 256;
    if (vox < 324) {
      int lp = vox / 81, k = vox - lp * 81;
      int kd = k / 9, kw = k - kd * 9;
      const float* sp = src + (pd * 9 + kd) * 2304 + (pw0 + lp) * 9 + kw;
      float xin[32];
      #pragma unroll
      for (int c2 = 0; c2 < 32; ++c2) xin[c2] = sp[c2 * 82944];
      #pragma unroll
      for (int o = 0; o < 32; ++o) {
        float s = bs[o];
        #pragma unroll
        for (int c2 = 0; c2 < 32; ++c2) s = fmaf(Ws[o * 32 + c2], xin[c2], s);
        Vs[(o * 4 + lp) * KPAD + k] = f2bf(s);
      }
    }
  }
  __syncthreads();

  // --- res_trans: P = LeakyReLU(Vs @ WeT^T), in place over wave-owned rows ---
  int wave = t >> 6, lane = t & 63;
  int m15 = lane & 15, quad = lane >> 4;
  short8 bw[6][3];
  #pragma unroll
  for (int j = 0; j < 6; ++j)
    #pragma unroll
    for (int ks = 0; ks < 3; ++ks)
      bw[j][ks] = *(const short8*)&WeT[(j * 16 + m15) * KPAD + ks * 32 + quad * 8];
  int wbase = wave * 32;
  short8 a[2][3];
  #pragma unroll
  for (int i2 = 0; i2 < 2; ++i2)
    #pragma unroll
    for (int ks = 0; ks < 3; ++ks)
      a[i2][ks] = *(const short8*)&Vs[(wbase + i2 * 16 + m15) * KPAD + ks * 32 + quad * 8];
  floatx4 pacc[2][6];
  #pragma unroll
  for (int i2 = 0; i2 < 2; ++i2)
    #pragma unroll
    for (int j = 0; j < 6; ++j) pacc[i2][j] = (floatx4){0.f, 0.f, 0.f, 0.f};
  #pragma unroll
  for (int ks = 0; ks < 3; ++ks)
    #pragma unroll
    for (int i2 = 0; i2 < 2; ++i2)
      #pragma unroll
      for (int j = 0; j < 6; ++j)
        pacc[i2][j] = __builtin_amdgcn_mfma_f32_16x16x32_bf16(a[i2][ks], bw[j][ks], pacc[i2][j], 0, 0, 0);
  // LeakyReLU + write back (cols 81..95 are exactly 0: WeT pad rows are 0)
  #pragma unroll
  for (int i2 = 0; i2 < 2; ++i2)
    #pragma unroll
    for (int j = 0; j < 6; ++j)
      #pragma unroll
      for (int reg = 0; reg < 4; ++reg) {
        int row = wbase + i2 * 16 + quad * 4 + reg;
        int col = j * 16 + m15;
        float v = pacc[i2][j][reg];
        v = v > 0.f ? v : 0.2f * v;
        Vs[row * KPAD + col] = f2bf(v);
      }
  __syncthreads();

  // --- coalesced P store: 128 rows x 12 short8; contiguous 768B runs per o-group ---
  for (int i = t; i < 1536; i += 256) {
    int r = i / 12, xx = i - r * 12;
    int o = r >> 2, lp = r & 3;
    size_t row = (size_t)(tensor * 32 + o) * 1024 + (l0 + lp);
    *(short8*)&Pg[row * VSTR + xx * 8] = *(const short8*)&Vs[r * KPAD + xx * 8];
  }
}

// ---------------- Kernel 2: att tile GEMM ----------------
// grid (8,8,32): 128(l1) x 128(l2) f32 out tile per channel. Pure stage + MFMA.
// LDS 52KB -> 3 blocks/CU.
__global__ __launch_bounds__(256, 3) void k_att(const u16* __restrict__ P,
                                                float* __restrict__ out) {
  __shared__ u16 pxs[128 * KPAD];   // 26624 B
  __shared__ u16 pys[128 * KPAD];   // 26624 B
  int t = threadIdx.x;
  int c = blockIdx.z;
  int l1b = blockIdx.y * 128, l2b = blockIdx.x * 128;
  const u16* vx = P + ((size_t)c        * 1024 + l1b) * VSTR;
  const u16* vy = P + ((size_t)(32 + c) * 1024 + l2b) * VSTR;

  for (int i = t; i < 1536; i += 256) {    // 128 rows x 12 short8 each buffer
    int r = i / 12, xx = i - r * 12;
    short8 a = *(const short8*)&vx[i * 8];  // i*8 == r*96 + xx*8
    short8 b = *(const short8*)&vy[i * 8];
    *(short8*)&pxs[r * KPAD + xx * 8] = a;
    *(short8*)&pys[r * KPAD + xx * 8] = b;
  }
  __syncthreads();

  int wave = t >> 6, lane = t & 63;
  int m15 = lane & 15, quad = lane >> 4;
  int wy = (wave >> 1) * 64, wx = (wave & 1) * 64;
  floatx4 acc[4][4];
  #pragma unroll
  for (int i = 0; i < 4; ++i)
    #pragma unroll
    for (int j = 0; j < 4; ++j) acc[i][j] = (floatx4){0.f, 0.f, 0.f, 0.f};

  #pragma unroll
  for (int ks = 0; ks < 3; ++ks) {
    short8 a[4], b[4];
    #pragma unroll
    for (int i = 0; i < 4; ++i)
      a[i] = *(const short8*)&pxs[(wy + i * 16 + m15) * KPAD + ks * 32 + quad * 8];
    #pragma unroll
    for (int j = 0; j < 4; ++j)
      b[j] = *(const short8*)&pys[(wx + j * 16 + m15) * KPAD + ks * 32 + quad * 8];
    #pragma unroll
    for (int i = 0; i < 4; ++i)
      #pragma unroll
      for (int j = 0; j < 4; ++j)
        acc[i][j] = __builtin_amdgcn_mfma_f32_16x16x32_bf16(a[i], b[j], acc[i][j], 0, 0, 0);
  }

  const float inv = 1.f / 81.f;
  #pragma unroll
  for (int i = 0; i < 4; ++i)
    #pragma unroll
    for (int j = 0; j < 4; ++j)
      #pragma unroll
      for (int reg = 0; reg < 4; ++reg) {
        int row = l1b + wy + i * 16 + quad * 4 + reg;
        int col = l2b + wx + j * 16 + m15;
        out[(c << 20) + (row << 10) + col] = acc[i][j][reg] * inv;
      }
}

extern "C" void kernel_launch(void* const* d_in, const int* in_sizes, int n_in,
                              void* d_out, int out_size, void* d_ws, size_t ws_size,
                              hipStream_t stream) {
  const float* x    = (const float*)d_in[0];
  const float* y    = (const float*)d_in[1];
  const float* Wimg = (const float*)d_in[2];
  const float* bimg = (const float*)d_in[3];
  const float* Wfea = (const float*)d_in[4];
  const float* bfea = (const float*)d_in[5];
  const float* W1   = (const float*)d_in[6];
  const float* W2   = (const float*)d_in[7];
  float* out = (float*)d_out;

  char* ws = (char*)d_ws;
  u16* wepad = (u16*)ws;                       //     19,968 B (96*104 bf16)
  u16* Pg    = (u16*)(ws + 32768);             // 12,582,912 B (65536 rows * 96 bf16)

  // No memset: pad zeros are written explicitly by k_weff (WeT pad) and k_fused
  // (P pad cols come out as LeakyReLU(0)=0 through the zero WeT pad rows).
  k_weff <<<dim3(39),       256, 0, stream>>>(W1, W2, wepad);
  k_fused<<<dim3(256, 2),   256, 0, stream>>>(x, y, Wimg, bimg, Wfea, bfea, wepad, Pg);
  k_att  <<<dim3(8, 8, 32), 256, 0, stream>>>(Pg, out);
}